// Round 4
// baseline (229.988 us; speedup 1.0000x reference)
//
#include <hip/hip_runtime.h>
#include <hip/hip_bf16.h>

// y[b, c] = (sum_k x[b,k] * W[c % 512, k]) + bias[c]
// R9: R8's split-K-wave K-loop + epilogue, with staging moved OFF the
// global_load_lds DMA path (measured saturated at ~19 B/cy/CU; ds_read is
// ~130 B/cy) onto reg-staging (T14), and the x fp32->bf16 convert FUSED:
//   - cost model (fit R5/R7/R8 per block-iter): t = 22.2 ns/KB (DMA) +
//     3.2 ns/KB (ds) -> DMA is 7x costlier per byte; kill the DMA.
//   - A: global_load_dwordx4 of raw fp32 -> v_perm truncate to bf16 ->
//     ds_write_b64 into the SAME swizzled LDS layout as R8 (write-side
//     swizzle; per-instr bank-conflict-free, verified on paper).
//   - B: global_load_dwordx4 of pre-converted bf16 -> ds_write_b128 (same
//     swizzle). Tiny convert_w kernel (12 MB, ~3 us) remains; the 96 MB
//     x-convert traffic (~20 us) is gone.
//   - Pipeline: 2-stage LDS ring, 1 barrier/iter. Loads for tile kk+2 issued
//     at end of iter kk (~1 iter of latency slack); cvt+ds_write of tile kk+1
//     during iter kk; only manual wait is lgkmcnt(0) before the barrier
//     (no vmcnt drain -- compiler places counted waits at register use).
//   - K-loop reads/MFMA (4x mfma_32x32x16, split-K-wave, amp 1.0), XCD
//     swizzle, and reduce-epilogue identical to R8 (passed, absmax 3.0).

typedef __bf16 bf8 __attribute__((ext_vector_type(8)));
typedef float f16v __attribute__((ext_vector_type(16)));
typedef unsigned int uint;
typedef unsigned short ushort;

constexpr int M = 4096;
constexpr int K = 4096;
constexpr int NS = 512;
constexpr int OUTF = 4096;
constexpr int BM = 64, BN = 64, BK = 64;
constexpr int NITER = K / BK;    // 64
constexpr int SSTR = 68;         // scratch row stride (floats)
constexpr int WSTR = 16 * SSTR;  // scratch per-wave-copy stride (floats)

#define PERM_HI2(hi, lo) __builtin_amdgcn_perm((hi), (lo), 0x07060302u)

// W only: fp32 -> bf16 (truncate), 8 elems/thread. 512*4096/8/256 = 1024 blocks.
__global__ __launch_bounds__(256)
void convert_w(const float* __restrict__ w, ushort* __restrict__ wb) {
  const size_t i = (size_t)blockIdx.x * 256 + threadIdx.x;
  const float* src = w + i * 8;
  ushort* dst = wb + i * 8;
  const uint4 a = *reinterpret_cast<const uint4*>(src);
  const uint4 b = *reinterpret_cast<const uint4*>(src + 4);
  uint4 o;
  o.x = PERM_HI2(a.y, a.x); o.y = PERM_HI2(a.w, a.z);
  o.z = PERM_HI2(b.y, b.x); o.w = PERM_HI2(b.w, b.z);
  *reinterpret_cast<uint4*>(dst) = o;
}

__global__ __launch_bounds__(256, 2)
void gemm_kernel(const float* __restrict__ x, const ushort* __restrict__ wb,
                 const float* __restrict__ bias, float* __restrict__ out) {
  // single LDS pool: 2-stage A (16 KB) + 2-stage B (16 KB) = 32 KB;
  // epilogue reuses it as float scratch (needs 17408 B).
  __shared__ __align__(16) ushort sh[2 * BM * BK + 2 * BN * BK];
  ushort* As = sh;                    // [2][BM*BK]
  ushort* Bs = sh + 2 * BM * BK;      // [2][BN*BK]

  // XCD swizzle: blockIdx&7 == mt&7 -> all 8 nt-blocks of an x-slab share an XCD.
  const int b  = blockIdx.x;                  // 512 blocks
  const int mt = ((b >> 6) << 3) | (b & 7);   // 0..63
  const int nt = (b >> 3) & 7;                // 0..7

  const int tid  = threadIdx.x;
  const int wv   = tid >> 6;
  const int lane = tid & 63;
  const int lr   = lane & 15;
  const int lq   = lane >> 4;
  const int gB   = lane & 7;

  // ---- staging maps (write-side swizzle: LDS chunk g^(r&7) holds global
  // 16B-bf16-chunk g of row r; identical layout to R8's DMA swizzle) ----
  // A: lane covers fp32 elems [lr*4, lr*4+4) of rows rA[j] = wv*16 + j*4 + lq.
  //    -> bf16 chunk g = lr>>1, half = lr&1; ds_write_b64.
  int rA[4], ldsA[4];
#pragma unroll
  for (int j = 0; j < 4; ++j) {
    rA[j] = wv * 16 + j * 4 + lq;
    ldsA[j] = (rA[j] * 8 + ((lr >> 1) ^ (rA[j] & 7))) * 8 + (lr & 1) * 4;
  }
  // B: lane covers bf16 elems [gB*8, gB*8+8) of rows rB[j]; ds_write_b128.
  int rB[2], ldsB[2];
#pragma unroll
  for (int j = 0; j < 2; ++j) {
    rB[j] = (wv * 2 + j) * 8 + (lane >> 3);
    ldsB[j] = (rB[j] * 8 + (gB ^ (rB[j] & 7))) * 8;
  }

  const float*  xT = x  + (size_t)(mt * BM) * K;
  const ushort* wT = wb + (size_t)(nt * BN) * K;

  uint4 ar[4], br[2];                 // raw regs for one in-flight tile

  auto loadT = [&](int tile) {
    const int ko = tile * BK;
#pragma unroll
    for (int j = 0; j < 4; ++j)
      ar[j] = *reinterpret_cast<const uint4*>(xT + (size_t)rA[j] * K + ko + lr * 4);
#pragma unroll
    for (int j = 0; j < 2; ++j)
      br[j] = *reinterpret_cast<const uint4*>(wT + (size_t)rB[j] * K + ko + gB * 8);
  };
  auto writeT = [&](int stg) {
    ushort* Ad = As + stg * (BM * BK);
    ushort* Bd = Bs + stg * (BN * BK);
#pragma unroll
    for (int j = 0; j < 4; ++j) {
      uint2 o;
      o.x = PERM_HI2(ar[j].y, ar[j].x);
      o.y = PERM_HI2(ar[j].w, ar[j].z);
      *reinterpret_cast<uint2*>(Ad + ldsA[j]) = o;
    }
#pragma unroll
    for (int j = 0; j < 2; ++j)
      *reinterpret_cast<uint4*>(Bd + ldsB[j]) = br[j];
  };

  // K-loop read geometry (identical to R8): wave wv owns k-slice
  // [wv*16, wv*16+16); lane reads global k-chunk q = 2*wv + hi at LDS chunk
  // q^(row&7), row&7 == lane&7.
  const int l31 = lane & 31;
  const int hi  = lane >> 5;
  const int coff = ((2 * wv + hi) ^ (lane & 7)) * 8;

  f16v acc[2][2] = {};

  // ---- prologue: tile 0 staged, tile 1 in flight ----
  loadT(0);
  writeT(0);                                   // compiler waits vmcnt at use
  loadT(1);
  asm volatile("s_waitcnt lgkmcnt(0)" ::: "memory");

  int st = 0;
  for (int kk = 0; kk < NITER; ++kk) {
    __builtin_amdgcn_s_barrier();              // publish tile kk (stage st)
    asm volatile("" ::: "memory");

    const ushort* aT = As + st * (BM * BK);
    const ushort* bT = Bs + st * (BN * BK);
    const bf8 a0 = *reinterpret_cast<const bf8*>(&aT[(l31)      * BK + coff]);
    const bf8 a1 = *reinterpret_cast<const bf8*>(&aT[(32 + l31) * BK + coff]);
    const bf8 b0 = *reinterpret_cast<const bf8*>(&bT[(l31)      * BK + coff]);
    const bf8 b1 = *reinterpret_cast<const bf8*>(&bT[(32 + l31) * BK + coff]);
    acc[0][0] = __builtin_amdgcn_mfma_f32_32x32x16_bf16(a0, b0, acc[0][0], 0, 0, 0);
    acc[0][1] = __builtin_amdgcn_mfma_f32_32x32x16_bf16(a0, b1, acc[0][1], 0, 0, 0);
    acc[1][0] = __builtin_amdgcn_mfma_f32_32x32x16_bf16(a1, b0, acc[1][0], 0, 0, 0);
    acc[1][1] = __builtin_amdgcn_mfma_f32_32x32x16_bf16(a1, b1, acc[1][1], 0, 0, 0);
    asm volatile("" ::: "memory");

    if (kk + 1 < NITER) {
      writeT(st ^ 1);                          // tile kk+1 -> other stage
      if (kk + 2 < NITER) loadT(kk + 2);       // next tile into raw regs
      asm volatile("s_waitcnt lgkmcnt(0)" ::: "memory");
    }
    st ^= 1;
  }

  // ---- epilogue: reduce 4 per-wave K-partials, add bias, store 8 replicas
  // (identical to R8) ----
  __syncthreads();
  float* scr = reinterpret_cast<float*>(sh);   // 17408 B <= 32 KB

  const int c4  = tid & 15;          // float4 column within 64-col tile
  const int r16 = tid >> 4;          // row within 16-row quarter
  const float4* bias4 = reinterpret_cast<const float4*>(bias);
  float4 bb[8];
#pragma unroll
  for (int rep = 0; rep < 8; ++rep)
    bb[rep] = bias4[rep * 128 + nt * 16 + c4];

#pragma unroll
  for (int rq = 0; rq < 4; ++rq) {                   // output rows [rq*16, +16)
    const int tm = rq >> 1, half = rq & 1;
#pragma unroll
    for (int tn = 0; tn < 2; ++tn)
#pragma unroll
      for (int j = 0; j < 8; ++j) {
        const int row16 = (j & 3) + 8 * (j >> 2) + 4 * hi;   // C/D row formula
        scr[wv * WSTR + row16 * SSTR + tn * 32 + l31] = acc[tm][tn][8 * half + j];
      }
    __syncthreads();
    float4 s;
    {
      const float4 p0 = *reinterpret_cast<const float4*>(&scr[0 * WSTR + r16 * SSTR + c4 * 4]);
      const float4 p1 = *reinterpret_cast<const float4*>(&scr[1 * WSTR + r16 * SSTR + c4 * 4]);
      const float4 p2 = *reinterpret_cast<const float4*>(&scr[2 * WSTR + r16 * SSTR + c4 * 4]);
      const float4 p3 = *reinterpret_cast<const float4*>(&scr[3 * WSTR + r16 * SSTR + c4 * 4]);
      s.x = (p0.x + p1.x) + (p2.x + p3.x);
      s.y = (p0.y + p1.y) + (p2.y + p3.y);
      s.z = (p0.z + p1.z) + (p2.z + p3.z);
      s.w = (p0.w + p1.w) + (p2.w + p3.w);
    }
    float* orow = out + (size_t)(mt * BM + rq * 16 + r16) * OUTF + nt * BN + c4 * 4;
#pragma unroll
    for (int rep = 0; rep < 8; ++rep) {
      float4 o;
      o.x = s.x + bb[rep].x; o.y = s.y + bb[rep].y;
      o.z = s.z + bb[rep].z; o.w = s.w + bb[rep].w;
      *reinterpret_cast<float4*>(orow + rep * NS) = o;
    }
    __syncthreads();                                 // scratch reused next round
  }
}

extern "C" void kernel_launch(void* const* d_in, const int* in_sizes, int n_in,
                              void* d_out, int out_size, void* d_ws, size_t ws_size,
                              hipStream_t stream) {
  (void)in_sizes; (void)n_in; (void)out_size; (void)ws_size;
  const float* x    = (const float*)d_in[0];
  const float* w    = (const float*)d_in[1];
  const float* bias = (const float*)d_in[2];
  float* out = (float*)d_out;

  ushort* wb = (ushort*)d_ws;       // 4 MB bf16 W (ws >= 4 MB)

  constexpr int convw_blocks = (int)((size_t)NS * K / 8 / 256);  // 1024
  convert_w<<<dim3(convw_blocks), dim3(256), 0, stream>>>(w, wb);
  gemm_kernel<<<dim3(64 * 8), dim3(256), 0, stream>>>(x, wb, bias, out);
}

// Round 5
// 212.631 us; speedup vs baseline: 1.0816x; 1.0816x over previous
//
#include <hip/hip_runtime.h>
#include <hip/hip_bf16.h>

// y[b, c] = (sum_k x[b,k] * W[c % 512, k]) + bias[c]
// R10: 128x128 tiles, split-K=2, 256 blocks (1/CU, 8 waves), DMA staging.
// Cost model (fit on R5/R7/R8, residual <1%): t_iter = 22.2 ns/KB (DMA) +
// 3.2 ns/KB (ds_read) per CU -> the binder is global_load_lds DMA bytes.
// 128^2 tiles quarter DMA-bytes/flop vs the 64^2 structure (R5/R8 ~52-58us).
//   - A staged as RAW fp32 via global_load_lds (R7-verified read path:
//     paired f4 ds_reads + v_perm truncate to bf16); the 96-MB x-convert
//     dispatch is eliminated. W keeps its 3-us bf16 convert.
//   - BK=32, 3-stage ring (72 KB static LDS -- R7-proven size), counted
//     s_waitcnt vmcnt(3) (3 DMAs/wave/iter), single barrier/iter, depth-2.
//   - split-K-wave layout 4m x 2n (wave tile 32x64, mfma_32x32x16), amp:
//     A 2x, B 2x -> reads ~64 KB/CU-iter (cheap per model).
//   - XCD grouping: all 8 blocks of one mt (4 nt x 2 splits) share blockIdx&7
//     -> x slab HBM-fetched once per XCD; split partials exchange in home L2.
//   - Cooperative combine (R6-proven ticket + spin; co-residency guaranteed
//     at 256 blocks): both splits write partials into replica slots 0/1,
//     ticket, spin till 2, read partner slot (L2-hit), add bias, each writes
//     a disjoint half of the 8 replicas (split0->odd, split1->even; write
//     sets verified non-conflicting with partner reads).
// Workspace: 4 MB wb + 512 B tickets (zeroed by convert_w block 0).

typedef __bf16 bf8 __attribute__((ext_vector_type(8)));
typedef float f4 __attribute__((ext_vector_type(4)));
typedef float f16v __attribute__((ext_vector_type(16)));
typedef unsigned int uint;
typedef unsigned short ushort;

constexpr int M = 4096;
constexpr int K = 4096;
constexpr int NS = 512;
constexpr int OUTF = 4096;
constexpr int BM = 128, BN = 128, BK = 32;
constexpr int SPLITS = 2;
constexpr int KSPL = K / SPLITS;    // 2048
constexpr int NITER = KSPL / BK;    // 64
constexpr int MT = M / BM;          // 32
constexpr int NT = NS / BN;         // 4
constexpr int NTILES = MT * NT;     // 128

#define PERM_HI2(hi, lo) __builtin_amdgcn_perm((hi), (lo), 0x07060302u)
// s_waitcnt imm: vmcnt[3:0]|expcnt[6:4]|lgkmcnt[11:8]|vmcnt[15:14]
#define WAITCNT_VM3 0xF73   // vmcnt<=3 (tile kk's 3 DMAs drained, kk+1 in flight)
#define WAITCNT_VM0 0xF70

__device__ __forceinline__ void async16(const void* g, void* l) {
  __builtin_amdgcn_global_load_lds(
      (const __attribute__((address_space(1))) void*)g,
      (__attribute__((address_space(3))) void*)l, 16, 0, 0);
}

// W only: fp32 -> bf16 (truncate), 8 elems/thread; block 0 zeroes tickets.
__global__ __launch_bounds__(256)
void convert_w(const float* __restrict__ w, ushort* __restrict__ wb,
               uint* __restrict__ tickets) {
  if (blockIdx.x == 0 && threadIdx.x < NTILES) tickets[threadIdx.x] = 0u;
  const size_t i = (size_t)blockIdx.x * 256 + threadIdx.x;
  const float* src = w + i * 8;
  ushort* dst = wb + i * 8;
  const uint4 a = *reinterpret_cast<const uint4*>(src);
  const uint4 b = *reinterpret_cast<const uint4*>(src + 4);
  uint4 o;
  o.x = PERM_HI2(a.y, a.x); o.y = PERM_HI2(a.w, a.z);
  o.z = PERM_HI2(b.y, b.x); o.w = PERM_HI2(b.w, b.z);
  *reinterpret_cast<uint4*>(dst) = o;
}

__global__ __launch_bounds__(512, 1)
void gemm_kernel(const float* __restrict__ x, const ushort* __restrict__ wb,
                 const float* __restrict__ bias, float* __restrict__ out,
                 uint* __restrict__ tickets) {
  __shared__ __align__(16) float  As[3][BM * BK];   // fp32 A, 16 KB/stage
  __shared__ __align__(16) ushort Bs[3][BN * BK];   // bf16 B,  8 KB/stage
  // total 72 KB static (R7-proven size), 1 block/CU

  // block map: b = (mt&7) + 8*((mt>>3)*8 + sp*4 + nt) -- all 8 blocks of an
  // mt (4 nt x 2 splits) share b&7 (one XCD under blockIdx%8 round-robin).
  const int b   = blockIdx.x;            // 256 blocks
  const int low = b & 7, h = b >> 3;     // h in [0,32)
  const int mt  = (h >> 3) * 8 + low;    // 0..31
  const int nt  = h & 3;                 // 0..3
  const int sp  = (h >> 2) & 1;          // split 0/1

  const int tid  = threadIdx.x;
  const int wv   = tid >> 6;             // 0..7
  const int lane = tid & 63;
  const int l31  = lane & 31;
  const int hi   = lane >> 5;

  // A DMA: tile = 128 rows x 32 fp32 = 1024 16B-chunks (8/row), 2 insts/wave.
  // LDS chunk (c&7) of row r holds global chunk (c&7)^(r&7).
  int goffA[2], llocA[2];
#pragma unroll
  for (int j = 0; j < 2; ++j) {
    const int c = (wv * 2 + j) * 64 + lane;
    const int r = c >> 3, g = (c & 7) ^ (r & 7);
    goffA[j] = r * K + g * 4;       // float units
    llocA[j] = c * 4;               // float units (linear dest)
  }
  // B DMA: tile = 128 rows x 32 bf16 = 512 chunks (4/row), 1 inst/wave.
  // LDS chunk (c&3) of row r holds global chunk (c&3)^((r>>1)&3) (row-pair
  // XOR spreads the 64B rows across banks).
  int goffB, llocB;
  {
    const int c = wv * 64 + lane;
    const int r = c >> 2, g = (c & 3) ^ ((r >> 1) & 3);
    goffB = r * K + g * 8;          // ushort units
    llocB = c * 8;
  }

  const float*  xT = x  + (size_t)(mt * BM) * K + sp * KSPL;
  const ushort* wT = wb + (size_t)(nt * BN) * K + sp * KSPL;

  auto issue = [&](int tile, int stg) {
    const int ko = tile * BK;
#pragma unroll
    for (int j = 0; j < 2; ++j) async16(xT + ko + goffA[j], &As[stg][llocA[j]]);
    async16(wT + ko + goffB, &Bs[stg][llocB]);
  };

  // wave layout 4m x 2n: wave tile 32 rows x 64 cols.
  const int wm   = (wv & 3) * 32;
  const int wn   = (wv >> 2) * 64;
  const int rowA = wm + l31;
  const int axor = l31 & 7;          // rowA & 7
  const int bxor = (l31 >> 1) & 3;   // (rowB >> 1) & 3  (wn, n*32 are mult of 32)
  const int rb0  = wn + l31, rb1 = wn + 32 + l31;

  f16v acc[2] = {};

  // prologue: tiles 0,1 into stages 0,1 (3 DMAs/wave each)
  issue(0, 0);
  issue(1, 1);

  int st = 0;
  for (int kk = 0; kk < NITER; ++kk) {
    if (kk + 1 < NITER) __builtin_amdgcn_s_waitcnt(WAITCNT_VM3);
    else                __builtin_amdgcn_s_waitcnt(WAITCNT_VM0);
    __builtin_amdgcn_s_barrier();      // publish tile kk
    asm volatile("" ::: "memory");
    if (kk + 2 < NITER) {              // reuse stage read 2 iters ago (safe)
      int s2 = st + 2; if (s2 >= 3) s2 -= 3;
      issue(kk + 2, s2);
    }

    const float*  aT = As[st];
    const ushort* bT = Bs[st];
#pragma unroll
    for (int ks = 0; ks < 2; ++ks) {
      // A: lane needs fp32 chunks q0,q0+1 (q0 even); slot ca holds q0.
      const int q0 = (ks * 2 + hi) * 2;
      const int ca = q0 ^ axor;
      const f4 a0 = *reinterpret_cast<const f4*>(&aT[rowA * BK + ca * 4]);
      const f4 a1 = *reinterpret_cast<const f4*>(&aT[rowA * BK + (ca ^ 1) * 4]);
      const uint* u0 = reinterpret_cast<const uint*>(&a0);
      const uint* u1 = reinterpret_cast<const uint*>(&a1);
      uint4 p;
      p.x = PERM_HI2(u0[1], u0[0]); p.y = PERM_HI2(u0[3], u0[2]);
      p.z = PERM_HI2(u1[1], u1[0]); p.w = PERM_HI2(u1[3], u1[2]);
      const bf8 af = __builtin_bit_cast(bf8, p);
      const int cb = ks * 2 + hi;
      const bf8 b0 = *reinterpret_cast<const bf8*>(&bT[rb0 * BK + (cb ^ bxor) * 8]);
      const bf8 b1 = *reinterpret_cast<const bf8*>(&bT[rb1 * BK + (cb ^ bxor) * 8]);
      acc[0] = __builtin_amdgcn_mfma_f32_32x32x16_bf16(af, b0, acc[0], 0, 0, 0);
      acc[1] = __builtin_amdgcn_mfma_f32_32x32x16_bf16(af, b1, acc[1], 0, 0, 0);
    }
    asm volatile("" ::: "memory");
    if (++st >= 3) st = 0;
  }

  // ---- split-K epilogue (cooperative pair combine) ----
  // C/D layout (m74, R8-verified): col = wn + n*32 + l31,
  // row = wm + (j&3) + 8*(j>>2) + 4*hi.
  const int colb = nt * BN + wn;                       // + n*32 + l31 (+ rep*NS)
  float* obase = out + (size_t)(mt * BM + wm) * OUTF;

  // 1) store fp32 partial into replica slot #sp (coalesced per 32 lanes)
#pragma unroll
  for (int n = 0; n < 2; ++n)
#pragma unroll
    for (int j = 0; j < 16; ++j) {
      const int rowf = (j & 3) + 8 * (j >> 2) + 4 * hi;
      obase[(size_t)rowf * OUTF + sp * NS + colb + n * 32 + l31] = acc[n][j];
    }

  // 2) ticket + spin (co-residency guaranteed: 256 blocks <= capacity)
  __syncthreads();                     // drain stores to L2
  if (tid == 0) {
    uint* tk = &tickets[mt * NT + nt];
    __hip_atomic_fetch_add(tk, 1u, __ATOMIC_ACQ_REL, __HIP_MEMORY_SCOPE_AGENT);
    while (__hip_atomic_load(tk, __ATOMIC_ACQUIRE, __HIP_MEMORY_SCOPE_AGENT) < SPLITS)
      __builtin_amdgcn_s_sleep(2);
  }
  __syncthreads();

  // 3) read partner slot, add bias, write our half of the 8 replicas.
  //    split0 -> odd reps {1,3,5,7} (never touches slot0 = partner's source);
  //    split1 -> even reps {0,2,4,6} (never touches slot1). Same-thread
  //    read-before-write on own addresses; ownership partition race-free.
  const int po = (sp ^ 1) * NS;
  float bv[2][4];
#pragma unroll
  for (int n = 0; n < 2; ++n)
#pragma unroll
    for (int i = 0; i < 4; ++i)
      bv[n][i] = bias[(2 * i + (sp ^ 1)) * NS + colb + n * 32 + l31];

#pragma unroll
  for (int n = 0; n < 2; ++n)
#pragma unroll
    for (int j = 0; j < 16; ++j) {
      const int rowf = (j & 3) + 8 * (j >> 2) + 4 * hi;
      const float s =
          acc[n][j] + obase[(size_t)rowf * OUTF + po + colb + n * 32 + l31];
#pragma unroll
      for (int i = 0; i < 4; ++i)
        obase[(size_t)rowf * OUTF + (2 * i + (sp ^ 1)) * NS + colb + n * 32 + l31] =
            s + bv[n][i];
    }
}

extern "C" void kernel_launch(void* const* d_in, const int* in_sizes, int n_in,
                              void* d_out, int out_size, void* d_ws, size_t ws_size,
                              hipStream_t stream) {
  (void)in_sizes; (void)n_in; (void)out_size; (void)ws_size;
  const float* x    = (const float*)d_in[0];
  const float* w    = (const float*)d_in[1];
  const float* bias = (const float*)d_in[2];
  float* out = (float*)d_out;

  ushort* wb = (ushort*)d_ws;                        // 4 MB bf16 W
  uint* tickets = (uint*)(wb + (size_t)NS * K);      // 512 B

  constexpr int convw_blocks = (int)((size_t)NS * K / 8 / 256);  // 1024
  convert_w<<<dim3(convw_blocks), dim3(256), 0, stream>>>(w, wb, tickets);
  gemm_kernel<<<dim3(NTILES * SPLITS), dim3(512), 0, stream>>>(x, wb, bias, out, tickets);
}

// Round 6
// 150.809 us; speedup vs baseline: 1.5250x; 1.4099x over previous
//
#include <hip/hip_runtime.h>
#include <hip/hip_bf16.h>

// y[b, c] = (sum_k x[b,k] * W[c % 512, k]) + bias[c]
// R11: m97-structure GEMM (128x128 tile, BK=64, 2-stage 64KB LDS ring,
// 2 barriers/iter, 8 global_load_lds insts/wave/iter = deep DMA queue) with
// split-K=4 -> 512 blocks (2 blocks/CU, R8-proven residency), plus a trivial
// combine kernel. Lessons baked in:
//   - R5/R8's ~22 ns/KB "DMA rate" was shallow-queue latency, not an engine
//     cap (m97 sustains ~87 B/cy/CU with 8 insts/wave/iter) -> go big-tile.
//   - 1 block/CU lockstep (R10) exposes DMA latency -> keep 2/CU.
//   - Cross-XCD ticket combine (R6) cost ~100us -> NO sync at all: gemm
//     writes fp32 partials into replica slot #sp of out (reps 0-3), then
//     combine_kernel does y[r][rep][c] = sum_sp out[r][sp][c] + bias[rep][c]
//     (in-place safe: each thread reads only addresses it alone writes).
//   - bf16 staging for BOTH operands (fp32-A DMA is the R7-proven 2x loser);
//     convert kernel unchanged from R0/R8.
//   - XCD co-location: all 16 blocks (4 nt x 4 sp) of one mt share b&7 ->
//     one 1-MB x-slab HBM fetch per XCD; W (4 MB) L2/L3-resident.

typedef __bf16 bf8 __attribute__((ext_vector_type(8)));
typedef float f4 __attribute__((ext_vector_type(4)));
typedef unsigned int uint;
typedef unsigned short ushort;

constexpr int M = 4096;
constexpr int K = 4096;
constexpr int NS = 512;
constexpr int OUTF = 4096;
constexpr int BM = 128, BN = 128, BK = 64;
constexpr int SPLITS = 4;
constexpr int KSPL = K / SPLITS;    // 1024
constexpr int NITER = KSPL / BK;    // 16
constexpr int MT = M / BM;          // 32
constexpr int NT = NS / BN;         // 4

#define PERM_HI2(hi, lo) __builtin_amdgcn_perm((hi), (lo), 0x07060302u)
// s_waitcnt imm: vmcnt[3:0]|expcnt[6:4]|lgkmcnt[11:8]|vmcnt[15:14]
#define WAITCNT_VM8 0xF78   // vmcnt<=8: tile kk's 8 DMAs drained, kk+1's in flight
#define WAITCNT_VM0 0xF70

__device__ __forceinline__ void async16(const ushort* g, ushort* l) {
  __builtin_amdgcn_global_load_lds(
      (const __attribute__((address_space(1))) void*)g,
      (__attribute__((address_space(3))) void*)l, 16, 0, 0);
}

// fp32 -> bf16 (truncate), 8 elems/thread; covers x then W exactly (R0-proven).
__global__ __launch_bounds__(256)
void convert_kernel(const float* __restrict__ x, const float* __restrict__ w,
                    ushort* __restrict__ xb, ushort* __restrict__ wb) {
  const size_t i = (size_t)blockIdx.x * 256 + threadIdx.x;
  constexpr size_t NX = (size_t)M * K / 8;
  const float* src;
  ushort* dst;
  if (i < NX) { src = x + i * 8; dst = xb + i * 8; }
  else        { const size_t j = i - NX; src = w + j * 8; dst = wb + j * 8; }
  const uint4 a = *reinterpret_cast<const uint4*>(src);
  const uint4 b = *reinterpret_cast<const uint4*>(src + 4);
  uint4 o;
  o.x = PERM_HI2(a.y, a.x); o.y = PERM_HI2(a.w, a.z);
  o.z = PERM_HI2(b.y, b.x); o.w = PERM_HI2(b.w, b.z);
  *reinterpret_cast<uint4*>(dst) = o;
}

__global__ __launch_bounds__(256, 2)
void gemm_kernel(const ushort* __restrict__ xb, const ushort* __restrict__ wb,
                 float* __restrict__ out) {
  __shared__ __align__(16) ushort As[2][BM * BK];   // 16 KB/stage
  __shared__ __align__(16) ushort Bs[2][BN * BK];   // 16 KB/stage  -> 64 KB total

  // block map: b = (mt&7) + 8*((mt>>3)*16 + sp*4 + nt)
  // -> the 16 blocks of one mt share b&7 (one XCD), x-slab fetched once/XCD.
  const int b   = blockIdx.x;          // 512 blocks
  const int low = b & 7, h = b >> 3;   // h in [0,64)
  const int mt  = (h >> 4) * 8 + low;  // 0..31
  const int sp  = (h >> 2) & 3;        // split 0..3
  const int nt  = h & 3;               // 0..3

  const int tid  = threadIdx.x;
  const int wv   = tid >> 6;           // 0..3
  const int lane = tid & 63;
  const int lr   = lane & 15;
  const int lq   = lane >> 4;

  // DMA staging: per matrix, tile = 128 rows x 64 bf16 = 1024 16B-chunks
  // (8/row); 4 insts/wave/matrix. LDS chunk c holds global chunk
  // ((c&7) ^ (row&7)) of row (c>>3) -- linear LDS dest, swizzled source (R5).
  int goff[4], lloc[4];
#pragma unroll
  for (int j = 0; j < 4; ++j) {
    const int c = (wv * 4 + j) * 64 + lane;
    const int r = c >> 3;
    const int g = (c & 7) ^ (r & 7);
    goff[j] = r * K + g * 8;
    lloc[j] = c * 8;
  }

  const ushort* xT = xb + (size_t)(mt * BM) * K + sp * KSPL;
  const ushort* wT = wb + (size_t)(nt * BN) * K + sp * KSPL;

  auto issue = [&](int tile, int stg) {
    const int ko = tile * BK;
#pragma unroll
    for (int j = 0; j < 4; ++j) {
      async16(xT + ko + goff[j], &As[stg][lloc[j]]);
      async16(wT + ko + goff[j], &Bs[stg][lloc[j]]);
    }
  };

  const int wm = (wv & 1) * 64;        // 2x2 wave grid, wave tile 64x64
  const int wn = (wv >> 1) * 64;

  f4 acc[4][4] = {};

  // prologue: tiles 0,1 into stages 0,1 (8 DMAs/wave each)
  issue(0, 0);
  issue(1, 1);

  int st = 0;
  for (int kk = 0; kk < NITER; ++kk) {
    if (kk + 1 < NITER) __builtin_amdgcn_s_waitcnt(WAITCNT_VM8);
    else                __builtin_amdgcn_s_waitcnt(WAITCNT_VM0);
    __builtin_amdgcn_s_barrier();      // publish tile kk (stage st)
    asm volatile("" ::: "memory");

    const ushort* aT = As[st];
    const ushort* bT = Bs[st];
#pragma unroll
    for (int t = 0; t < 2; ++t) {
      const int sc = ((t * 4 + lq) ^ (lr & 7)) * 8;   // R5-proven read swizzle
      bf8 af[4], bfv[4];
#pragma unroll
      for (int mf = 0; mf < 4; ++mf)
        af[mf] = *reinterpret_cast<const bf8*>(&aT[(wm + mf * 16 + lr) * BK + sc]);
#pragma unroll
      for (int nf = 0; nf < 4; ++nf)
        bfv[nf] = *reinterpret_cast<const bf8*>(&bT[(wn + nf * 16 + lr) * BK + sc]);
#pragma unroll
      for (int mf = 0; mf < 4; ++mf)
#pragma unroll
        for (int nf = 0; nf < 4; ++nf)
          acc[mf][nf] = __builtin_amdgcn_mfma_f32_16x16x32_bf16(af[mf], bfv[nf], acc[mf][nf], 0, 0, 0);
    }
    asm volatile("" ::: "memory");
    __builtin_amdgcn_s_barrier();      // all waves done READING stage st
    asm volatile("" ::: "memory");
    if (kk + 2 < NITER) issue(kk + 2, st);   // stage st now reusable
    st ^= 1;
  }

  // ---- epilogue: write fp32 partial into replica slot #sp of out ----
  // C/D layout (16x16x32, R5/m89-verified): row = wm+mf*16+lq*4+r,
  // col = wn+nf*16+lr. Stores are 16-lane (64 B) contiguous runs.
  float* pb = out + (size_t)(mt * BM) * OUTF + sp * NS + nt * BN;
#pragma unroll
  for (int mf = 0; mf < 4; ++mf)
#pragma unroll
    for (int nf = 0; nf < 4; ++nf)
#pragma unroll
      for (int r = 0; r < 4; ++r)
        pb[(size_t)(wm + mf * 16 + lq * 4 + r) * OUTF + wn + nf * 16 + lr] =
            acc[mf][nf][r];
}

// y[r][rep][c] = sum_{sp<4} out[r][sp][c] + bias[rep][c], rep = 0..7.
// In-place safe: thread (r,c4) reads only addresses it alone writes.
__global__ __launch_bounds__(256)
void combine_kernel(const float* __restrict__ bias, float* __restrict__ out) {
  const int idx = blockIdx.x * 256 + threadIdx.x;   // 2048 blocks -> 524288
  const int row = idx >> 7;            // 0..4095
  const int c4  = idx & 127;           // float4-col within 512
  float* orow = out + (size_t)row * OUTF;
  float4 s;
  {
    const float4 p0 = *reinterpret_cast<const float4*>(orow + 0 * NS + c4 * 4);
    const float4 p1 = *reinterpret_cast<const float4*>(orow + 1 * NS + c4 * 4);
    const float4 p2 = *reinterpret_cast<const float4*>(orow + 2 * NS + c4 * 4);
    const float4 p3 = *reinterpret_cast<const float4*>(orow + 3 * NS + c4 * 4);
    s.x = (p0.x + p1.x) + (p2.x + p3.x);
    s.y = (p0.y + p1.y) + (p2.y + p3.y);
    s.z = (p0.z + p1.z) + (p2.z + p3.z);
    s.w = (p0.w + p1.w) + (p2.w + p3.w);
  }
  const float4* bias4 = reinterpret_cast<const float4*>(bias);
#pragma unroll
  for (int rep = 0; rep < 8; ++rep) {
    const float4 bb = bias4[rep * 128 + c4];
    float4 o;
    o.x = s.x + bb.x; o.y = s.y + bb.y;
    o.z = s.z + bb.z; o.w = s.w + bb.w;
    *reinterpret_cast<float4*>(orow + rep * NS + c4 * 4) = o;
  }
}

extern "C" void kernel_launch(void* const* d_in, const int* in_sizes, int n_in,
                              void* d_out, int out_size, void* d_ws, size_t ws_size,
                              hipStream_t stream) {
  (void)in_sizes; (void)n_in; (void)out_size; (void)ws_size;
  const float* x    = (const float*)d_in[0];
  const float* w    = (const float*)d_in[1];
  const float* bias = (const float*)d_in[2];
  float* out = (float*)d_out;

  ushort* xb = (ushort*)d_ws;                       // 32 MB bf16 x
  ushort* wb = (ushort*)d_ws + (size_t)M * K;       // 4 MB bf16 W (ws >= 36 MB)

  constexpr int conv_blocks = (int)(((size_t)M * K / 8 + (size_t)NS * K / 8) / 256); // 9216
  convert_kernel<<<dim3(conv_blocks), dim3(256), 0, stream>>>(x, w, xb, wb);
  gemm_kernel<<<dim3(MT * NT * SPLITS), dim3(256), 0, stream>>>(xb, wb, out);
  combine_kernel<<<dim3(M * (NS / 4) / 256), dim3(256), 0, stream>>>(bias, out);
}